// Round 1
// baseline (9357.799 us; speedup 1.0000x reference)
//
#include <hip/hip_runtime.h>
#include <math.h>

// SPDNet forward, fully fused: one wave (64 lanes) per batch element.
// Pipeline per matrix: X1=w1^T x w1 -> Jacobi eig (n=32) -> clip ->
// X2=(w2^T U)diag(mu)(w2^T U)^T -> Jacobi eig (n=16) -> clip ->
// X3=(w3^T U)diag(mu)(w3^T U)^T -> serial Jacobi 4x4 -> logeig -> feat/fc/logsoftmax.

#define NSWEEP32 9
#define NSWEEP16 8
#define NSWEEP4  10

// Parallel cyclic Jacobi on an NxN symmetric matrix in LDS (stride N+1),
// accumulating eigenvectors into U (stride N+1). One wave, round-robin
// tournament ordering: M=N/2 disjoint pairs per round, N-1 rounds/sweep.
template<int N>
__device__ __forceinline__ void jacobi_wave(float* A, float* U, int lane, int nsweeps,
                                            float* cA, float* sA, int* pA, int* qA) {
  constexpr int M   = N / 2;
  constexpr int NR  = N - 1;     // rounds per sweep (odd)
  constexpr int STR = N + 1;     // padded stride
  constexpr int TPP = (M * N) / 64;  // tasks per lane per phase
  for (int sw = 0; sw < nsweeps; ++sw) {
    for (int r = 0; r < NR; ++r) {
      // Phase 1: lanes 0..M-1 compute rotation (c,s) for their pair.
      // Round-robin: fixed player N-1 pairs with istar = (inv2 * r) mod NR,
      // (inv2 = N/2 since 2*(N/2) = N == 1 mod N-1); others: istar +/- k.
      if (lane < M) {
        int istar = (M * r) % NR;
        int p, q;
        if (lane == 0) { p = N - 1; q = istar; }
        else {
          p = istar + lane; if (p >= NR) p -= NR;
          q = istar - lane; if (q < 0)   q += NR;
        }
        float app = A[p * STR + p];
        float aqq = A[q * STR + q];
        float apq = A[p * STR + q];
        float c = 1.f, s = 0.f;
        if (apq != 0.f) {
          float theta = 0.5f * (aqq - app) / apq;
          // t = smaller root of t^2 + 2*theta*t - 1 = 0.
          // theta overflow -> t = 0 -> identity rotation (graceful).
          float t = copysignf(1.f, theta) / (fabsf(theta) + sqrtf(1.f + theta * theta));
          c = rsqrtf(1.f + t * t);
          s = t * c;
        }
        cA[lane] = c; sA[lane] = s; pA[lane] = p; qA[lane] = q;
      }
      __syncthreads();
      // Phase 2: row update A <- J^T A. M*N tasks, disjoint elements.
      #pragma unroll
      for (int t = 0; t < TPP; ++t) {
        int task = lane + 64 * t;
        int k = task / N, j = task % N;
        float s = sA[k];
        if (s != 0.f) {
          float c = cA[k]; int p = pA[k], q = qA[k];
          float ap = A[p * STR + j], aq = A[q * STR + j];
          A[p * STR + j] = c * ap - s * aq;
          A[q * STR + j] = s * ap + c * aq;
        }
      }
      __syncthreads();
      // Phase 3: col update A <- A J, and U <- U J.
      #pragma unroll
      for (int t = 0; t < TPP; ++t) {
        int task = lane + 64 * t;
        int k = task / N, i = task % N;
        float s = sA[k];
        if (s != 0.f) {
          float c = cA[k]; int p = pA[k], q = qA[k];
          float ap = A[i * STR + p], aq = A[i * STR + q];
          A[i * STR + p] = c * ap - s * aq;
          A[i * STR + q] = s * ap + c * aq;
          float up = U[i * STR + p], uq = U[i * STR + q];
          U[i * STR + p] = c * up - s * uq;
          U[i * STR + q] = s * up + c * uq;
        }
      }
      __syncthreads();
    }
  }
}

__launch_bounds__(64)
__global__ void spdnet_kernel(const float* __restrict__ x,
                              const float* __restrict__ w1,
                              const float* __restrict__ w2,
                              const float* __restrict__ w3,
                              const float* __restrict__ fcw,
                              float* __restrict__ out,
                              int B) {
  const int b    = blockIdx.x;
  const int lane = threadIdx.x;

  __shared__ float A[32 * 33];
  __shared__ float U[32 * 33];
  __shared__ float cA[16], sA[16];
  __shared__ int   pA[16], qA[16];
  __shared__ float mu[32];
  __shared__ float w2s[32 * 16];
  __shared__ float w3s[16 * 4];
  __shared__ float G2s[4 * 16];
  __shared__ float X3s[16];

  const float* xb = x + (size_t)b * 1024;

  // ---- load x -> A, w1 -> U, stage small weights ----
  #pragma unroll
  for (int t = 0; t < 16; ++t) {
    int idx = lane + 64 * t;
    int r = idx >> 5, c = idx & 31;
    A[r * 33 + c] = xb[idx];
    U[r * 33 + c] = w1[idx];
  }
  #pragma unroll
  for (int t = 0; t < 8; ++t) w2s[lane + 64 * t] = w2[lane + 64 * t];
  w3s[lane] = w3[lane];
  __syncthreads();

  // ---- T = w1^T * x : T[i][k] = sum_j w1[j][i] * x[j][k] ----
  float treg[16];
  #pragma unroll
  for (int t = 0; t < 16; ++t) {
    int idx = lane + 64 * t;
    int i = idx >> 5, k = idx & 31;
    float acc = 0.f;
    #pragma unroll
    for (int j = 0; j < 32; ++j) acc += U[j * 33 + i] * A[j * 33 + k];
    treg[t] = acc;
  }
  __syncthreads();
  #pragma unroll
  for (int t = 0; t < 16; ++t) {
    int idx = lane + 64 * t;
    A[(idx >> 5) * 33 + (idx & 31)] = treg[t];  // A = T
  }
  __syncthreads();

  // ---- X1 = T * w1 : X1[i][l] = sum_k T[i][k] * w1[k][l] ----
  #pragma unroll
  for (int t = 0; t < 16; ++t) {
    int idx = lane + 64 * t;
    int i = idx >> 5, l = idx & 31;
    float acc = 0.f;
    #pragma unroll
    for (int k = 0; k < 32; ++k) acc += A[i * 33 + k] * U[k * 33 + l];
    treg[t] = acc;
  }
  __syncthreads();
  #pragma unroll
  for (int t = 0; t < 16; ++t) {
    int idx = lane + 64 * t;
    int i = idx >> 5, l = idx & 31;
    A[i * 33 + l] = treg[t];              // A = X1
    U[i * 33 + l] = (i == l) ? 1.f : 0.f; // U = I
  }
  __syncthreads();

  // ---- eig #1 (n=32) ----
  jacobi_wave<32>(A, U, lane, NSWEEP32, cA, sA, pA, qA);

  // ---- ReEig clip + fused bilinear: X2 = G diag(mu) G^T, G = w2^T U ----
  if (lane < 32) mu[lane] = fmaxf(A[lane * 33 + lane], 1e-4f);
  __syncthreads();
  // G[a][k] = sum_j w2[j][a] U[j][k]  (16x32), store into A rows 0..15
  #pragma unroll
  for (int t = 0; t < 8; ++t) {
    int idx = lane + 64 * t;       // 0..511
    int a = idx >> 5, k = idx & 31;
    float acc = 0.f;
    #pragma unroll
    for (int j = 0; j < 32; ++j) acc += w2s[j * 16 + a] * U[j * 33 + k];
    A[a * 33 + k] = acc;           // safe: only reads U/w2s, writes A
  }
  __syncthreads();
  // X2[a][b] = sum_k G[a][k] mu[k] G[b][k]  (16x16)
  float x2reg[4];
  #pragma unroll
  for (int t = 0; t < 4; ++t) {
    int idx = lane + 64 * t;       // 0..255
    int a = idx >> 4, bb = idx & 15;
    float acc = 0.f;
    #pragma unroll
    for (int k = 0; k < 32; ++k) acc += A[a * 33 + k] * mu[k] * A[bb * 33 + k];
    x2reg[t] = acc;
  }
  __syncthreads();
  #pragma unroll
  for (int t = 0; t < 4; ++t) {
    int idx = lane + 64 * t;
    int a = idx >> 4, bb = idx & 15;
    A[a * 17 + bb] = x2reg[t];               // A = X2, stride 17
    U[a * 17 + bb] = (a == bb) ? 1.f : 0.f;  // U = I, stride 17
  }
  __syncthreads();

  // ---- eig #2 (n=16) ----
  jacobi_wave<16>(A, U, lane, NSWEEP16, cA, sA, pA, qA);

  // ---- ReEig clip + fused bilinear: X3 = G2 diag(mu) G2^T, G2 = w3^T U ----
  if (lane < 16) mu[lane] = fmaxf(A[lane * 17 + lane], 1e-4f);
  __syncthreads();
  {
    int a = lane >> 4, k = lane & 15;   // 4x16 = 64 outputs, one per lane
    float acc = 0.f;
    #pragma unroll
    for (int j = 0; j < 16; ++j) acc += w3s[j * 4 + a] * U[j * 17 + k];
    G2s[a * 16 + k] = acc;
  }
  __syncthreads();
  if (lane < 16) {
    int a = lane >> 2, bb = lane & 3;
    float acc = 0.f;
    #pragma unroll
    for (int k = 0; k < 16; ++k) acc += G2s[a * 16 + k] * mu[k] * G2s[bb * 16 + k];
    X3s[lane] = acc;
  }
  __syncthreads();

  // ---- stage 3: serial 4x4 Jacobi + LogEig + fc + log_softmax (lane 0) ----
  if (lane == 0) {
    float Am[4][4], V[4][4];
    #pragma unroll
    for (int i = 0; i < 4; ++i)
      #pragma unroll
      for (int j = 0; j < 4; ++j) {
        Am[i][j] = X3s[i * 4 + j];
        V[i][j] = (i == j) ? 1.f : 0.f;
      }
    for (int sw = 0; sw < NSWEEP4; ++sw) {
      #pragma unroll
      for (int p = 0; p < 3; ++p) {
        #pragma unroll
        for (int q = p + 1; q < 4; ++q) {
          float apq = Am[p][q];
          if (apq != 0.f) {
            float theta = 0.5f * (Am[q][q] - Am[p][p]) / apq;
            float t = copysignf(1.f, theta) / (fabsf(theta) + sqrtf(1.f + theta * theta));
            float c = rsqrtf(1.f + t * t), s = t * c;
            #pragma unroll
            for (int j = 0; j < 4; ++j) {
              float ap = Am[p][j], aq = Am[q][j];
              Am[p][j] = c * ap - s * aq;
              Am[q][j] = s * ap + c * aq;
            }
            #pragma unroll
            for (int i = 0; i < 4; ++i) {
              float ap = Am[i][p], aq = Am[i][q];
              Am[i][p] = c * ap - s * aq;
              Am[i][q] = s * ap + c * aq;
              float up = V[i][p], uq = V[i][q];
              V[i][p] = c * up - s * uq;
              V[i][q] = s * up + c * uq;
            }
          }
        }
      }
    }
    float lm[4];
    #pragma unroll
    for (int i = 0; i < 4; ++i) lm[i] = logf(fmaxf(Am[i][i], 1e-10f));
    float feat[16];
    #pragma unroll
    for (int i = 0; i < 4; ++i)
      #pragma unroll
      for (int j = 0; j < 4; ++j) {
        float acc = 0.f;
        #pragma unroll
        for (int k = 0; k < 4; ++k) acc += V[i][k] * lm[k] * V[j][k];
        feat[i * 4 + j] = acc;
      }
    float z0 = 0.f, z1 = 0.f;
    #pragma unroll
    for (int f = 0; f < 16; ++f) {
      z0 += feat[f] * fcw[f * 2 + 0];
      z1 += feat[f] * fcw[f * 2 + 1];
    }
    float mx = fmaxf(z0, z1);
    float lse = mx + logf(expf(z0 - mx) + expf(z1 - mx));
    out[b * 2 + 0] = z0 - lse;
    out[b * 2 + 1] = z1 - lse;
    float* fo = out + (size_t)2 * B + (size_t)b * 16;
    #pragma unroll
    for (int f = 0; f < 16; ++f) fo[f] = feat[f];
  }
}

extern "C" void kernel_launch(void* const* d_in, const int* in_sizes, int n_in,
                              void* d_out, int out_size, void* d_ws, size_t ws_size,
                              hipStream_t stream) {
  (void)n_in; (void)d_ws; (void)ws_size; (void)out_size;
  const float* x   = (const float*)d_in[0];
  const float* w1  = (const float*)d_in[1];
  const float* w2  = (const float*)d_in[2];
  const float* w3  = (const float*)d_in[3];
  const float* fcw = (const float*)d_in[4];
  float* out = (float*)d_out;
  int B = in_sizes[0] / 1024;
  spdnet_kernel<<<B, 64, 0, stream>>>(x, w1, w2, w3, fcw, out, B);
}

// Round 2
// 9037.386 us; speedup vs baseline: 1.0355x; 1.0355x over previous
//
#include <hip/hip_runtime.h>
#include <math.h>

// SPDNet forward, fully fused: one wave (64 lanes) per batch element.
// X1=w1^T x w1 -> Jacobi eig (n=32) -> clip -> X2=G diag(mu) G^T (G=w2^T U)
// -> Jacobi eig (n=16) -> clip -> X3 -> serial Jacobi 4x4 -> logeig -> fc.
//
// Jacobi: pair-per-lane-group mapping. Rotation params computed redundantly
// by each lane of a pair (no LDS round-trip for c/s/p/q). Rounds whose pairs
// are all below tol are skipped via ballot; sweeps break when fully inactive.

#define MAXSW32 10
#define MAXSW16 9
#define MAXSW4  8

// A-scratch layout (floats), stage boundaries guarantee no overlap:
//   [0..1055]    stage1 matrix (stride 33) / stage2 matrix (stride 17, [0..271])
//   [288..351]   w3 staging (after G dead)
//   [352..415]   G2 (4x16)
//   [416..431]   X3 (4x4)
//   [432..447]   mu16
//   [528..1039]  w2 staging (after eig1)
//   [1056..1087] mu32
__launch_bounds__(64)
__global__ void spdnet_kernel(const float* __restrict__ x,
                              const float* __restrict__ w1,
                              const float* __restrict__ w2,
                              const float* __restrict__ w3,
                              const float* __restrict__ fcw,
                              float* __restrict__ out,
                              int B);

template<int N>
__device__ __forceinline__ void jacobi_wave(float* A, float* U, int lane,
                                            float tol, int maxsweep) {
  constexpr int M   = N / 2;      // pairs per round
  constexpr int NR  = N - 1;      // rounds per sweep
  constexpr int STR = N + 1;      // padded stride
  constexpr int LPP = 64 / M;     // lanes per pair
  constexpr int CPL = N / LPP;    // tasks per lane per phase
  const int k   = lane / LPP;
  const int sub = lane % LPP;
  // Round-robin tournament state, advanced incrementally (istar += M mod NR).
  int pp = (k == 0) ? (N - 1) : k;
  int qq = (k == 0) ? 0 : (NR - k);
  for (int sw = 0; sw < maxsweep; ++sw) {
    bool anyact = false;
    for (int r = 0; r < NR; ++r) {
      const int p = pp, q = qq;
      // advance for next round
      if (k != 0) { pp += M; if (pp >= NR) pp -= NR; }
      qq += M; if (qq >= NR) qq -= NR;

      const int p33 = p * STR, q33 = q * STR;
      float app = A[p33 + p];
      float aqq = A[q33 + q];
      float apq = A[p33 + q];
      bool active = fabsf(apq) > tol;
      float c = 1.f, s = 0.f;
      if (active) {
        float theta = 0.5f * (aqq - app) / apq;
        float t = copysignf(1.f, theta) / (fabsf(theta) + sqrtf(1.f + theta * theta));
        c = rsqrtf(1.f + t * t);
        s = t * c;
      }
      unsigned long long msk = __ballot(active);
      if (msk == 0ull) continue;   // whole round converged
      anyact = true;
      __syncthreads();
      // Phase 2: row update A <- J^T A (disjoint rows across pairs).
      #pragma unroll
      for (int t = 0; t < CPL; ++t) {
        int j = sub + LPP * t;
        if (active) {
          float ap = A[p33 + j], aq = A[q33 + j];
          A[p33 + j] = c * ap - s * aq;
          A[q33 + j] = s * ap + c * aq;
        }
      }
      __syncthreads();
      // Phase 3: col update A <- A J, and U <- U J (disjoint cols).
      #pragma unroll
      for (int t = 0; t < CPL; ++t) {
        int base = (sub + LPP * t) * STR;
        if (active) {
          float ap = A[base + p], aq = A[base + q];
          A[base + p] = c * ap - s * aq;
          A[base + q] = s * ap + c * aq;
          float up = U[base + p], uq = U[base + q];
          U[base + p] = c * up - s * uq;
          U[base + q] = s * up + c * uq;
        }
      }
      __syncthreads();
    }
    if (!anyact) break;
  }
}

__device__ __forceinline__ float wave_max(float v) {
  #pragma unroll
  for (int off = 32; off; off >>= 1) v = fmaxf(v, __shfl_xor(v, off));
  return v;
}

__launch_bounds__(64)
__global__ void spdnet_kernel(const float* __restrict__ x,
                              const float* __restrict__ w1,
                              const float* __restrict__ w2,
                              const float* __restrict__ w3,
                              const float* __restrict__ fcw,
                              float* __restrict__ out,
                              int B) {
  const int b    = blockIdx.x;
  const int lane = threadIdx.x;

  __shared__ float A[1088];
  __shared__ float U[1056];

  const float* xb = x + (size_t)b * 1024;

  // ---- prefetch small weights into registers ----
  float w2r[8];
  #pragma unroll
  for (int t = 0; t < 8; ++t) w2r[t] = w2[lane + 64 * t];
  float w3r = w3[lane];

  // ---- load x -> A, w1 -> U (stride 33) ----
  #pragma unroll
  for (int t = 0; t < 16; ++t) {
    int idx = lane + 64 * t;
    int r = idx >> 5, c = idx & 31;
    A[r * 33 + c] = xb[idx];
    U[r * 33 + c] = w1[idx];
  }
  __syncthreads();

  // ---- T = w1^T * x ----
  float treg[16];
  #pragma unroll
  for (int t = 0; t < 16; ++t) {
    int idx = lane + 64 * t;
    int i = idx >> 5, kk = idx & 31;
    float acc = 0.f;
    #pragma unroll
    for (int j = 0; j < 32; ++j) acc += U[j * 33 + i] * A[j * 33 + kk];
    treg[t] = acc;
  }
  __syncthreads();
  #pragma unroll
  for (int t = 0; t < 16; ++t) {
    int idx = lane + 64 * t;
    A[(idx >> 5) * 33 + (idx & 31)] = treg[t];  // A = T
  }
  __syncthreads();

  // ---- X1 = T * w1 ----
  #pragma unroll
  for (int t = 0; t < 16; ++t) {
    int idx = lane + 64 * t;
    int i = idx >> 5, l = idx & 31;
    float acc = 0.f;
    #pragma unroll
    for (int kk = 0; kk < 32; ++kk) acc += A[i * 33 + kk] * U[kk * 33 + l];
    treg[t] = acc;
  }
  __syncthreads();
  #pragma unroll
  for (int t = 0; t < 16; ++t) {
    int idx = lane + 64 * t;
    int i = idx >> 5, l = idx & 31;
    A[i * 33 + l] = treg[t];              // A = X1
    U[i * 33 + l] = (i == l) ? 1.f : 0.f; // U = I
  }
  __syncthreads();

  // ---- tol1 from max |diag X1| ----
  float tol1 = 1e-7f * wave_max(fabsf(A[(lane & 31) * 34]));

  // ---- eig #1 (n=32) ----
  jacobi_wave<32>(A, U, lane, tol1, MAXSW32);

  // ---- clip eigenvalues -> mu32 @ A[1056], stage w2 @ A[528] ----
  __syncthreads();
  if (lane < 32) A[1056 + lane] = fmaxf(A[lane * 34], 1e-4f);
  #pragma unroll
  for (int t = 0; t < 8; ++t) A[528 + lane + 64 * t] = w2r[t];
  __syncthreads();

  // ---- G = w2^T U (16x32) into A rows 0..15 (stride 33) ----
  #pragma unroll
  for (int t = 0; t < 8; ++t) {
    int idx = lane + 64 * t;       // 0..511
    int a = idx >> 5, kk = idx & 31;
    float acc = 0.f;
    #pragma unroll
    for (int j = 0; j < 32; ++j) acc += A[528 + j * 16 + a] * U[j * 33 + kk];
    treg[t] = acc;
  }
  __syncthreads();
  #pragma unroll
  for (int t = 0; t < 8; ++t) {
    int idx = lane + 64 * t;
    A[(idx >> 5) * 33 + (idx & 31)] = treg[t];  // A rows 0..15 = G
  }
  __syncthreads();

  // ---- X2 = G diag(mu) G^T (16x16) ----
  float x2reg[4];
  #pragma unroll
  for (int t = 0; t < 4; ++t) {
    int idx = lane + 64 * t;       // 0..255
    int a = idx >> 4, bb = idx & 15;
    float acc = 0.f;
    #pragma unroll
    for (int kk = 0; kk < 32; ++kk)
      acc += A[a * 33 + kk] * A[1056 + kk] * A[bb * 33 + kk];
    x2reg[t] = acc;
  }
  __syncthreads();
  #pragma unroll
  for (int t = 0; t < 4; ++t) {
    int idx = lane + 64 * t;
    int a = idx >> 4, bb = idx & 15;
    A[a * 17 + bb] = x2reg[t];               // A = X2 (stride 17)
    U[a * 17 + bb] = (a == bb) ? 1.f : 0.f;  // U = I
  }
  A[288 + lane] = w3r;                       // stage w3 (G now dead)
  __syncthreads();

  // ---- tol2 ----
  float tol2 = 1e-7f * wave_max(fabsf(A[(lane & 15) * 18]));

  // ---- eig #2 (n=16) ----
  jacobi_wave<16>(A, U, lane, tol2, MAXSW16);

  // ---- clip -> mu16 @ A[432] ----
  __syncthreads();
  if (lane < 16) A[432 + lane] = fmaxf(A[lane * 18], 1e-4f);
  __syncthreads();

  // ---- G2 = w3^T U (4x16) @ A[352] ----
  {
    int a = lane >> 4, kk = lane & 15;
    float acc = 0.f;
    #pragma unroll
    for (int j = 0; j < 16; ++j) acc += A[288 + j * 4 + a] * U[j * 17 + kk];
    A[352 + a * 16 + kk] = acc;
  }
  __syncthreads();

  // ---- X3 = G2 diag(mu16) G2^T (4x4) @ A[416] ----
  if (lane < 16) {
    int a = lane >> 2, bb = lane & 3;
    float acc = 0.f;
    #pragma unroll
    for (int kk = 0; kk < 16; ++kk)
      acc += A[352 + a * 16 + kk] * A[432 + kk] * A[352 + bb * 16 + kk];
    A[416 + lane] = acc;
  }
  __syncthreads();

  // ---- stage 3: serial 4x4 Jacobi + LogEig + fc + log_softmax (lane 0) ----
  if (lane == 0) {
    float Am[4][4], V[4][4];
    float maxd = 0.f;
    #pragma unroll
    for (int i = 0; i < 4; ++i) {
      #pragma unroll
      for (int j = 0; j < 4; ++j) {
        Am[i][j] = A[416 + i * 4 + j];
        V[i][j] = (i == j) ? 1.f : 0.f;
      }
      maxd = fmaxf(maxd, fabsf(Am[i][i]));
    }
    float tol3 = 1e-7f * maxd;
    for (int sw = 0; sw < MAXSW4; ++sw) {
      bool any = false;
      #pragma unroll
      for (int p = 0; p < 3; ++p) {
        #pragma unroll
        for (int q = p + 1; q < 4; ++q) {
          float apq = Am[p][q];
          if (fabsf(apq) > tol3) {
            any = true;
            float theta = 0.5f * (Am[q][q] - Am[p][p]) / apq;
            float t = copysignf(1.f, theta) / (fabsf(theta) + sqrtf(1.f + theta * theta));
            float c = rsqrtf(1.f + t * t), s = t * c;
            #pragma unroll
            for (int j = 0; j < 4; ++j) {
              float ap = Am[p][j], aq = Am[q][j];
              Am[p][j] = c * ap - s * aq;
              Am[q][j] = s * ap + c * aq;
            }
            #pragma unroll
            for (int i = 0; i < 4; ++i) {
              float ap = Am[i][p], aq = Am[i][q];
              Am[i][p] = c * ap - s * aq;
              Am[i][q] = s * ap + c * aq;
              float up = V[i][p], uq = V[i][q];
              V[i][p] = c * up - s * uq;
              V[i][q] = s * up + c * uq;
            }
          }
        }
      }
      if (!any) break;
    }
    float lm[4];
    #pragma unroll
    for (int i = 0; i < 4; ++i) lm[i] = logf(fmaxf(Am[i][i], 1e-10f));
    float feat[16];
    #pragma unroll
    for (int i = 0; i < 4; ++i)
      #pragma unroll
      for (int j = 0; j < 4; ++j) {
        float acc = 0.f;
        #pragma unroll
        for (int kk = 0; kk < 4; ++kk) acc += V[i][kk] * lm[kk] * V[j][kk];
        feat[i * 4 + j] = acc;
      }
    float z0 = 0.f, z1 = 0.f;
    #pragma unroll
    for (int f = 0; f < 16; ++f) {
      z0 += feat[f] * fcw[f * 2 + 0];
      z1 += feat[f] * fcw[f * 2 + 1];
    }
    float mx = fmaxf(z0, z1);
    float lse = mx + logf(expf(z0 - mx) + expf(z1 - mx));
    out[b * 2 + 0] = z0 - lse;
    out[b * 2 + 1] = z1 - lse;
    float* fo = out + (size_t)2 * B + (size_t)b * 16;
    #pragma unroll
    for (int f = 0; f < 16; ++f) fo[f] = feat[f];
  }
}

extern "C" void kernel_launch(void* const* d_in, const int* in_sizes, int n_in,
                              void* d_out, int out_size, void* d_ws, size_t ws_size,
                              hipStream_t stream) {
  (void)n_in; (void)d_ws; (void)ws_size; (void)out_size;
  const float* x   = (const float*)d_in[0];
  const float* w1  = (const float*)d_in[1];
  const float* w2  = (const float*)d_in[2];
  const float* w3  = (const float*)d_in[3];
  const float* fcw = (const float*)d_in[4];
  float* out = (float*)d_out;
  int B = in_sizes[0] / 1024;
  spdnet_kernel<<<B, 64, 0, stream>>>(x, w1, w2, w3, fcw, out, B);
}

// Round 3
// 3339.212 us; speedup vs baseline: 2.8024x; 2.7064x over previous
//
#include <hip/hip_runtime.h>
#include <math.h>

// SPDNet forward, one wave (64 lanes) per batch element, one-sided (Hestenes)
// Jacobi. G's columns are orthogonalized in place; eigenvalues are column
// norms, eigenvectors are normalized columns -- no eigenvector matrix, no row
// updates, all column traffic is ds_read/write_b128. Column stride 36 (n=32)
// / 20 (n=16) keeps 16B alignment and spreads bank groups (col+chunk)%8.
//
// Pipeline: X1 = w1^T x w1 (col-major, register-blocked)
//   -> jac32 (one-sided) -> Z = (w2^T g_k)*sqrt(mu_k)/lam_k -> M2 = Z Z^T
//   -> jac16 -> Y = (w3^T g2_k)*sqrt(mu2_k)/lam2_k -> X3 = Y Y^T
//   -> lane-0 serial 4x4 two-sided Jacobi -> logeig -> fc -> log_softmax.

#define MAXSW32 10
#define MAXSW16 9
#define MAXSW4  8

__device__ __forceinline__ float shfl_xor_f(float v, int m) { return __shfl_xor(v, m, 64); }
__device__ __forceinline__ float dot4(float4 a, float4 b) {
  return a.x * b.x + a.y * b.y + a.z * b.z + a.w * b.w;
}
__device__ __forceinline__ void axpy4(float4& a, float xv, float4 w) {
  a.x += xv * w.x; a.y += xv * w.y; a.z += xv * w.z; a.w += xv * w.w;
}

// One-sided Jacobi, n=32, column stride 36. 16 pairs x 4 lanes.
__device__ __forceinline__ void jac32(float* __restrict__ G, float* __restrict__ nrm,
                                      int lane, int maxsw) {
  const int k = lane >> 2, sub = lane & 3;
  const int o0 = 4 * sub, o1 = 4 * sub + 16;
  int pp = (k == 0) ? 31 : k;
  int qq = (k == 0) ? 0 : (31 - k);
  for (int sw = 0; sw < maxsw; ++sw) {
    bool anyact = false;
    for (int r = 0; r < 31; ++r) {
      const int p = pp, q = qq;
      if (k != 0) { pp += 16; if (pp >= 31) pp -= 31; }
      qq += 16; if (qq >= 31) qq -= 31;
      const int pb = p * 36, qb = q * 36;
      float4 gp0 = *(const float4*)(G + pb + o0);
      float4 gp1 = *(const float4*)(G + pb + o1);
      float4 gq0 = *(const float4*)(G + qb + o0);
      float4 gq1 = *(const float4*)(G + qb + o1);
      float d = dot4(gp0, gq0) + dot4(gp1, gq1);
      d += shfl_xor_f(d, 1);
      d += shfl_xor_f(d, 2);
      float dpp = nrm[p], dqq = nrm[q];
      bool active = (d * d > 1e-14f * dpp * dqq);
      if (__ballot(active) == 0ull) continue;
      anyact = true;
      if (active) {
        float tau = 0.5f * (dqq - dpp) / d;
        float t = copysignf(1.f, tau) / (fabsf(tau) + sqrtf(1.f + tau * tau));
        float c = rsqrtf(1.f + t * t), s = t * c;
        float4 np0, np1, nq0, nq1;
        np0.x = c * gp0.x - s * gq0.x; nq0.x = s * gp0.x + c * gq0.x;
        np0.y = c * gp0.y - s * gq0.y; nq0.y = s * gp0.y + c * gq0.y;
        np0.z = c * gp0.z - s * gq0.z; nq0.z = s * gp0.z + c * gq0.z;
        np0.w = c * gp0.w - s * gq0.w; nq0.w = s * gp0.w + c * gq0.w;
        np1.x = c * gp1.x - s * gq1.x; nq1.x = s * gp1.x + c * gq1.x;
        np1.y = c * gp1.y - s * gq1.y; nq1.y = s * gp1.y + c * gq1.y;
        np1.z = c * gp1.z - s * gq1.z; nq1.z = s * gp1.z + c * gq1.z;
        np1.w = c * gp1.w - s * gq1.w; nq1.w = s * gp1.w + c * gq1.w;
        *(float4*)(G + pb + o0) = np0;
        *(float4*)(G + pb + o1) = np1;
        *(float4*)(G + qb + o0) = nq0;
        *(float4*)(G + qb + o1) = nq1;
        if (sub == 0) {
          float cs2 = 2.f * c * s * d, cc = c * c, ss = s * s;
          nrm[p] = cc * dpp - cs2 + ss * dqq;
          nrm[q] = ss * dpp + cs2 + cc * dqq;
        }
      }
      __syncthreads();
    }
    if (!anyact) break;
  }
  __syncthreads();
}

// One-sided Jacobi, n=16, column stride 20. 8 pairs x 8 lanes.
__device__ __forceinline__ void jac16(float* __restrict__ G, float* __restrict__ nrm,
                                      int lane, int maxsw) {
  const int k = lane >> 3, sub = lane & 7;
  const int o = 2 * sub;
  int pp = (k == 0) ? 15 : k;
  int qq = (k == 0) ? 0 : (15 - k);
  for (int sw = 0; sw < maxsw; ++sw) {
    bool anyact = false;
    for (int r = 0; r < 15; ++r) {
      const int p = pp, q = qq;
      if (k != 0) { pp += 8; if (pp >= 15) pp -= 15; }
      qq += 8; if (qq >= 15) qq -= 15;
      const int pb = p * 20 + o, qb = q * 20 + o;
      float2 gp = *(const float2*)(G + pb);
      float2 gq = *(const float2*)(G + qb);
      float d = gp.x * gq.x + gp.y * gq.y;
      d += shfl_xor_f(d, 1);
      d += shfl_xor_f(d, 2);
      d += shfl_xor_f(d, 4);
      float dpp = nrm[p], dqq = nrm[q];
      bool active = (d * d > 1e-14f * dpp * dqq);
      if (__ballot(active) == 0ull) continue;
      anyact = true;
      if (active) {
        float tau = 0.5f * (dqq - dpp) / d;
        float t = copysignf(1.f, tau) / (fabsf(tau) + sqrtf(1.f + tau * tau));
        float c = rsqrtf(1.f + t * t), s = t * c;
        float2 np, nq;
        np.x = c * gp.x - s * gq.x; nq.x = s * gp.x + c * gq.x;
        np.y = c * gp.y - s * gq.y; nq.y = s * gp.y + c * gq.y;
        *(float2*)(G + pb) = np;
        *(float2*)(G + qb) = nq;
        if (sub == 0) {
          float cs2 = 2.f * c * s * d, cc = c * c, ss = s * s;
          nrm[p] = cc * dpp - cs2 + ss * dqq;
          nrm[q] = ss * dpp + cs2 + cc * dqq;
        }
      }
      __syncthreads();
    }
    if (!anyact) break;
  }
  __syncthreads();
}

__launch_bounds__(64)
__global__ void spdnet_kernel(const float* __restrict__ x,
                              const float* __restrict__ w1,
                              const float* __restrict__ w2,
                              const float* __restrict__ w3,
                              const float* __restrict__ fcw,
                              float* __restrict__ out,
                              int B) {
  const int b    = blockIdx.x;
  const int lane = threadIdx.x;

  // R0: xs -> G (32 cols x 36) -> M2/G2 (16 cols x 20)
  // R1: w1s (rows as cols, 32x36) -> Z(32x20=640) + w3s@640(80) + Y@720(64) + X3@784(16)
  // R2: T (32x36) -> w2s (16 cols x 36 = 576)
  __shared__ float R0[1152];
  __shared__ float R1[1152];
  __shared__ float R2[1152];
  __shared__ float NRM[32];

  const float* xb = x + (size_t)b * 1024;
  const int kc = lane >> 1, h = lane & 1, hb = h * 16;

  // ---- stage x -> R0 (x symmetric: row-major == col-major), w1 rows -> R1 cols ----
  #pragma unroll
  for (int t = 0; t < 4; ++t) {
    int i4 = lane + 64 * t;          // float4 index 0..255
    int r = i4 >> 3, c4 = i4 & 7;
    float4 xv = ((const float4*)xb)[i4];
    float4 wv = ((const float4*)w1)[i4];
    *(float4*)(R0 + r * 36 + 4 * c4) = xv;
    *(float4*)(R1 + r * 36 + 4 * c4) = wv;
  }
  __syncthreads();

  // ---- T[:,k] = sum_j x[j][k] * w1row_j ; lane (kc, h) owns half-column ----
  float4 a0 = {0.f, 0.f, 0.f, 0.f}, a1 = a0, a2 = a0, a3 = a0;
  #pragma unroll
  for (int jc = 0; jc < 8; ++jc) {
    float4 xq = *(const float4*)(R0 + kc * 36 + 4 * jc);
    #pragma unroll
    for (int u = 0; u < 4; ++u) {
      float xv = (u == 0) ? xq.x : (u == 1) ? xq.y : (u == 2) ? xq.z : xq.w;
      const float* wr = R1 + (4 * jc + u) * 36 + hb;
      axpy4(a0, xv, *(const float4*)(wr));
      axpy4(a1, xv, *(const float4*)(wr + 4));
      axpy4(a2, xv, *(const float4*)(wr + 8));
      axpy4(a3, xv, *(const float4*)(wr + 12));
    }
  }
  *(float4*)(R2 + kc * 36 + hb)      = a0;
  *(float4*)(R2 + kc * 36 + hb + 4)  = a1;
  *(float4*)(R2 + kc * 36 + hb + 8)  = a2;
  *(float4*)(R2 + kc * 36 + hb + 12) = a3;
  __syncthreads();

  // ---- X1[:,l] = sum_k w1[k][l] * T[:,k] ; l = kc. Store G into R0. ----
  a0 = {0.f, 0.f, 0.f, 0.f}; a1 = a0; a2 = a0; a3 = a0;
  #pragma unroll
  for (int kk = 0; kk < 32; ++kk) {
    float wv = R1[kk * 36 + kc];
    const float* tc = R2 + kk * 36 + hb;
    axpy4(a0, wv, *(const float4*)(tc));
    axpy4(a1, wv, *(const float4*)(tc + 4));
    axpy4(a2, wv, *(const float4*)(tc + 8));
    axpy4(a3, wv, *(const float4*)(tc + 12));
  }
  *(float4*)(R0 + kc * 36 + hb)      = a0;
  *(float4*)(R0 + kc * 36 + hb + 4)  = a1;
  *(float4*)(R0 + kc * 36 + hb + 8)  = a2;
  *(float4*)(R0 + kc * 36 + hb + 12) = a3;
  // column norms from the registers we just produced
  float nv = dot4(a0, a0) + dot4(a1, a1) + dot4(a2, a2) + dot4(a3, a3);
  nv += shfl_xor_f(nv, 1);
  if (h == 0) NRM[kc] = nv;
  __syncthreads();   // all R1/R2 reads done before restaging

  // ---- stage w2 (transposed: col a contiguous) into R2, w3 into R1+640 ----
  #pragma unroll
  for (int t = 0; t < 8; ++t) {
    int idx = lane + 64 * t;
    int j = idx >> 4, a = idx & 15;
    R2[a * 36 + j] = w2[idx];
  }
  {
    int a = lane & 3, j = lane >> 2;
    R1[640 + a * 20 + j] = w3[lane];
  }
  __syncthreads();

  // ---- eig #1: one-sided Jacobi on G (n=32) ----
  jac32(R0, NRM, lane, MAXSW32);

  // ---- extraction: lam = ||g_k||, mu = max(lam,1e-4); Z[:,k] = (w2^T g_k)*sqrt(mu)/lam ----
  {
    float g[16];
    #pragma unroll
    for (int c = 0; c < 4; ++c) {
      float4 v = *(const float4*)(R0 + kc * 36 + hb + 4 * c);
      g[4 * c] = v.x; g[4 * c + 1] = v.y; g[4 * c + 2] = v.z; g[4 * c + 3] = v.w;
    }
    float dpp = 0.f;
    #pragma unroll
    for (int i = 0; i < 16; ++i) dpp += g[i] * g[i];
    dpp += shfl_xor_f(dpp, 1);
    float lam = sqrtf(dpp);
    float mu  = fmaxf(lam, 1e-4f);
    float sc  = sqrtf(mu) / fmaxf(lam, 1e-30f);
    #pragma unroll
    for (int a = 0; a < 16; ++a) {
      const float* wr = R2 + a * 36 + hb;
      float part = 0.f;
      #pragma unroll
      for (int c = 0; c < 4; ++c) {
        float4 wv = *(const float4*)(wr + 4 * c);
        part += g[4 * c] * wv.x + g[4 * c + 1] * wv.y + g[4 * c + 2] * wv.z + g[4 * c + 3] * wv.w;
      }
      part += shfl_xor_f(part, 1);
      if (h == 0) R1[kc * 20 + a] = part * sc;   // Z col-major (k-major), scaled
    }
  }
  __syncthreads();

  // ---- M2 = Z Z^T (16x16) into R0, col-major stride 20 ----
  {
    const int a = lane & 15, b0 = (lane >> 4) * 4;
    float m0 = 0.f, m1 = 0.f, m2 = 0.f, m3 = 0.f;
    #pragma unroll
    for (int kk = 0; kk < 32; ++kk) {
      float za = R1[kk * 20 + a];
      float4 zb = *(const float4*)(R1 + kk * 20 + b0);
      m0 += za * zb.x; m1 += za * zb.y; m2 += za * zb.z; m3 += za * zb.w;
    }
    __syncthreads();   // G reads (Z pass) complete before overwriting R0
    R0[(b0 + 0) * 20 + a] = m0;
    R0[(b0 + 1) * 20 + a] = m1;
    R0[(b0 + 2) * 20 + a] = m2;
    R0[(b0 + 3) * 20 + a] = m3;
  }
  __syncthreads();

  // ---- norms of M2 columns ----
  if (lane < 32) {
    float4 v0 = *(const float4*)(R0 + kc * 20 + 8 * h);
    float4 v1 = *(const float4*)(R0 + kc * 20 + 8 * h + 4);
    float n2 = dot4(v0, v0) + dot4(v1, v1);
    n2 += shfl_xor_f(n2, 1);
    if (h == 0) NRM[kc] = n2;
  }
  __syncthreads();

  // ---- eig #2: one-sided Jacobi on M2 (n=16) ----
  jac16(R0, NRM, lane, MAXSW16);

  // ---- Y[a][k] = (w3_col_a . g2_k) * sqrt(mu2)/lam2 ; X3 = Y Y^T ----
  {
    const int k3 = (lane >> 2) & 15, a3 = lane & 3;
    float dpp2 = 0.f, dotv = 0.f;
    #pragma unroll
    for (int c = 0; c < 4; ++c) {
      float4 gv = *(const float4*)(R0 + k3 * 20 + 4 * c);
      float4 wv = *(const float4*)(R1 + 640 + a3 * 20 + 4 * c);
      dpp2 += dot4(gv, gv);
      dotv += dot4(gv, wv);
    }
    float lam2 = sqrtf(dpp2);
    float mu2  = fmaxf(lam2, 1e-4f);
    float sc2  = sqrtf(mu2) / fmaxf(lam2, 1e-30f);
    R1[720 + k3 * 4 + a3] = dotv * sc2;   // Y, k-major stride 4
  }
  __syncthreads();
  if (lane < 16) {
    int a = lane >> 2, b2 = lane & 3;
    float s = 0.f;
    #pragma unroll
    for (int kk = 0; kk < 16; ++kk)
      s += R1[720 + kk * 4 + a] * R1[720 + kk * 4 + b2];
    R1[784 + lane] = s;
  }
  __syncthreads();

  // ---- stage 3: serial 4x4 two-sided Jacobi + LogEig + fc + log_softmax ----
  if (lane == 0) {
    float Am[4][4], V[4][4];
    float maxd = 0.f;
    #pragma unroll
    for (int i = 0; i < 4; ++i) {
      #pragma unroll
      for (int j = 0; j < 4; ++j) {
        Am[i][j] = R1[784 + i * 4 + j];
        V[i][j] = (i == j) ? 1.f : 0.f;
      }
      maxd = fmaxf(maxd, fabsf(Am[i][i]));
    }
    float tol3 = 1e-7f * maxd;
    for (int sw = 0; sw < MAXSW4; ++sw) {
      bool any = false;
      #pragma unroll
      for (int p = 0; p < 3; ++p) {
        #pragma unroll
        for (int q = p + 1; q < 4; ++q) {
          float apq = Am[p][q];
          if (fabsf(apq) > tol3) {
            any = true;
            float theta = 0.5f * (Am[q][q] - Am[p][p]) / apq;
            float t = copysignf(1.f, theta) / (fabsf(theta) + sqrtf(1.f + theta * theta));
            float c = rsqrtf(1.f + t * t), s = t * c;
            #pragma unroll
            for (int j = 0; j < 4; ++j) {
              float ap = Am[p][j], aq = Am[q][j];
              Am[p][j] = c * ap - s * aq;
              Am[q][j] = s * ap + c * aq;
            }
            #pragma unroll
            for (int i = 0; i < 4; ++i) {
              float ap = Am[i][p], aq = Am[i][q];
              Am[i][p] = c * ap - s * aq;
              Am[i][q] = s * ap + c * aq;
              float up = V[i][p], uq = V[i][q];
              V[i][p] = c * up - s * uq;
              V[i][q] = s * up + c * uq;
            }
          }
        }
      }
      if (!any) break;
    }
    float lm[4];
    #pragma unroll
    for (int i = 0; i < 4; ++i) lm[i] = logf(fmaxf(Am[i][i], 1e-10f));
    float feat[16];
    #pragma unroll
    for (int i = 0; i < 4; ++i)
      #pragma unroll
      for (int j = 0; j < 4; ++j) {
        float acc2 = 0.f;
        #pragma unroll
        for (int kk = 0; kk < 4; ++kk) acc2 += V[i][kk] * lm[kk] * V[j][kk];
        feat[i * 4 + j] = acc2;
      }
    float z0 = 0.f, z1 = 0.f;
    #pragma unroll
    for (int f = 0; f < 16; ++f) {
      z0 += feat[f] * fcw[f * 2 + 0];
      z1 += feat[f] * fcw[f * 2 + 1];
    }
    float mx = fmaxf(z0, z1);
    float lse = mx + logf(expf(z0 - mx) + expf(z1 - mx));
    out[b * 2 + 0] = z0 - lse;
    out[b * 2 + 1] = z1 - lse;
    float* fo = out + (size_t)2 * B + (size_t)b * 16;
    #pragma unroll
    for (int f = 0; f < 16; ++f) fo[f] = feat[f];
  }
}

extern "C" void kernel_launch(void* const* d_in, const int* in_sizes, int n_in,
                              void* d_out, int out_size, void* d_ws, size_t ws_size,
                              hipStream_t stream) {
  (void)n_in; (void)d_ws; (void)ws_size; (void)out_size;
  const float* x   = (const float*)d_in[0];
  const float* w1  = (const float*)d_in[1];
  const float* w2  = (const float*)d_in[2];
  const float* w3  = (const float*)d_in[3];
  const float* fcw = (const float*)d_in[4];
  float* out = (float*)d_out;
  int B = in_sizes[0] / 1024;
  spdnet_kernel<<<B, 64, 0, stream>>>(x, w1, w2, w3, fcw, out, B);
}

// Round 4
// 2219.917 us; speedup vs baseline: 4.2154x; 1.5042x over previous
//
#include <hip/hip_runtime.h>
#include <math.h>

// SPDNet forward, one wave (64 lanes) per batch element, one-sided (Hestenes)
// Jacobi. Columns orthogonalized in place; eigenvalues = column norms,
// eigenvectors = normalized columns. All column traffic ds_read/write_b128.
// Rotations use the divide-free form t = sign(tau)*d / (|tau|+sqrt(tau^2+d^2))
// with raw v_rcp/v_rsq/v_sqrt (no IEEE div/sqrt fixup sequences).
//
// LDS: R0[1152] matrix buffer (stride 36 / 20), R1[1216] weights+Z, NRM[32].
// ~9.6 KB/wave -> ~16 waves/CU.

#define MAXSW32 8
#define MAXSW16 8
#define MAXSW4  8
#define JTOL2   1e-12f

__device__ __forceinline__ float shfl_xor_f(float v, int m) { return __shfl_xor(v, m, 64); }
__device__ __forceinline__ float dot4(float4 a, float4 b) {
  return a.x * b.x + a.y * b.y + a.z * b.z + a.w * b.w;
}
__device__ __forceinline__ void axpy4(float4& a, float xv, float4 w) {
  a.x += xv * w.x; a.y += xv * w.y; a.z += xv * w.z; a.w += xv * w.w;
}
// Jacobi rotation from off-diag dot d and norms dpp,dqq. Divide-free.
__device__ __forceinline__ void rot_cs(float d, float dpp, float dqq,
                                       float& c, float& s) {
  float tau = 0.5f * (dqq - dpp);
  float r   = __builtin_amdgcn_sqrtf(fmaf(tau, tau, d * d));
  float den = fabsf(tau) + r;
  float tnum = __uint_as_float(__float_as_uint(d) ^
                               (__float_as_uint(tau) & 0x80000000u));
  float t = tnum * __builtin_amdgcn_rcpf(den);
  c = __builtin_amdgcn_rsqf(fmaf(t, t, 1.f));
  s = t * c;
}

// One-sided Jacobi, n=32, column stride 36. 16 pairs x 4 lanes.
__device__ __forceinline__ void jac32(float* __restrict__ G, float* __restrict__ nrm,
                                      int lane) {
  const int k = lane >> 2, sub = lane & 3;
  const int o0 = 4 * sub, o1 = 4 * sub + 16;
  int pp = (k == 0) ? 31 : k;
  int qq = (k == 0) ? 0 : (31 - k);
  for (int sw = 0; sw < MAXSW32; ++sw) {
    bool anyact = false;
    for (int r = 0; r < 31; ++r) {
      const int p = pp, q = qq;
      if (k != 0) { pp += 16; if (pp >= 31) pp -= 31; }
      qq += 16; if (qq >= 31) qq -= 31;
      const int pb = p * 36, qb = q * 36;
      float dpp = nrm[p], dqq = nrm[q];
      float4 gp0 = *(const float4*)(G + pb + o0);
      float4 gp1 = *(const float4*)(G + pb + o1);
      float4 gq0 = *(const float4*)(G + qb + o0);
      float4 gq1 = *(const float4*)(G + qb + o1);
      float d = dot4(gp0, gq0) + dot4(gp1, gq1);
      d += shfl_xor_f(d, 1);
      d += shfl_xor_f(d, 2);
      bool active = (d * d > JTOL2 * dpp * dqq);
      if (__ballot(active) == 0ull) continue;
      anyact = true;
      if (active) {
        float c, s;
        rot_cs(d, dpp, dqq, c, s);
        float4 np0, np1, nq0, nq1;
        np0.x = c * gp0.x - s * gq0.x; nq0.x = s * gp0.x + c * gq0.x;
        np0.y = c * gp0.y - s * gq0.y; nq0.y = s * gp0.y + c * gq0.y;
        np0.z = c * gp0.z - s * gq0.z; nq0.z = s * gp0.z + c * gq0.z;
        np0.w = c * gp0.w - s * gq0.w; nq0.w = s * gp0.w + c * gq0.w;
        np1.x = c * gp1.x - s * gq1.x; nq1.x = s * gp1.x + c * gq1.x;
        np1.y = c * gp1.y - s * gq1.y; nq1.y = s * gp1.y + c * gq1.y;
        np1.z = c * gp1.z - s * gq1.z; nq1.z = s * gp1.z + c * gq1.z;
        np1.w = c * gp1.w - s * gq1.w; nq1.w = s * gp1.w + c * gq1.w;
        *(float4*)(G + pb + o0) = np0;
        *(float4*)(G + pb + o1) = np1;
        *(float4*)(G + qb + o0) = nq0;
        *(float4*)(G + qb + o1) = nq1;
        if (sub == 0) {
          float cs2 = 2.f * c * s * d, cc = c * c, ss = s * s;
          nrm[p] = cc * dpp - cs2 + ss * dqq;
          nrm[q] = ss * dpp + cs2 + cc * dqq;
        }
      }
      __syncthreads();
    }
    if (!anyact) break;
  }
  __syncthreads();
}

// One-sided Jacobi, n=16, column stride 20. 8 pairs x 8 lanes.
__device__ __forceinline__ void jac16(float* __restrict__ G, float* __restrict__ nrm,
                                      int lane) {
  const int k = lane >> 3, sub = lane & 7;
  const int o = 2 * sub;
  int pp = (k == 0) ? 15 : k;
  int qq = (k == 0) ? 0 : (15 - k);
  for (int sw = 0; sw < MAXSW16; ++sw) {
    bool anyact = false;
    for (int r = 0; r < 15; ++r) {
      const int p = pp, q = qq;
      if (k != 0) { pp += 8; if (pp >= 15) pp -= 15; }
      qq += 8; if (qq >= 15) qq -= 15;
      const int pb = p * 20 + o, qb = q * 20 + o;
      float dpp = nrm[p], dqq = nrm[q];
      float2 gp = *(const float2*)(G + pb);
      float2 gq = *(const float2*)(G + qb);
      float d = gp.x * gq.x + gp.y * gq.y;
      d += shfl_xor_f(d, 1);
      d += shfl_xor_f(d, 2);
      d += shfl_xor_f(d, 4);
      bool active = (d * d > JTOL2 * dpp * dqq);
      if (__ballot(active) == 0ull) continue;
      anyact = true;
      if (active) {
        float c, s;
        rot_cs(d, dpp, dqq, c, s);
        float2 np, nq;
        np.x = c * gp.x - s * gq.x; nq.x = s * gp.x + c * gq.x;
        np.y = c * gp.y - s * gq.y; nq.y = s * gp.y + c * gq.y;
        *(float2*)(G + pb) = np;
        *(float2*)(G + qb) = nq;
        if (sub == 0) {
          float cs2 = 2.f * c * s * d, cc = c * c, ss = s * s;
          nrm[p] = cc * dpp - cs2 + ss * dqq;
          nrm[q] = ss * dpp + cs2 + cc * dqq;
        }
      }
      __syncthreads();
    }
    if (!anyact) break;
  }
  __syncthreads();
}

__launch_bounds__(64)
__global__ void spdnet_kernel(const float* __restrict__ x,
                              const float* __restrict__ w1,
                              const float* __restrict__ w2,
                              const float* __restrict__ w3,
                              const float* __restrict__ fcw,
                              float* __restrict__ out,
                              int B) {
  const int b    = blockIdx.x;
  const int lane = threadIdx.x;

  // R0: x -> L -> G (32 cols x 36) -> M2 (16 cols x 20) + w3s@1024(80)
  // R1: w1 (rows, stride 36) -> w2s [0..576) + Z @576 (32 cols x 20) -> Y@0(64) + X3@64(16)
  __shared__ float R0[1152];
  __shared__ float R1[1216];
  __shared__ float NRM[32];

  const float* xb = x + (size_t)b * 1024;
  const int kc = lane >> 1, h = lane & 1, hb = h * 16;

  // ---- stage x -> R0, w1 -> R1 (both row-major, stride 36) ----
  #pragma unroll
  for (int t = 0; t < 4; ++t) {
    int i4 = lane + 64 * t;          // float4 index 0..255
    int r = i4 >> 3, c4 = i4 & 7;
    float4 xv = ((const float4*)xb)[i4];
    float4 wv = ((const float4*)w1)[i4];
    *(float4*)(R0 + r * 36 + 4 * c4) = xv;
    *(float4*)(R1 + r * 36 + 4 * c4) = wv;
  }
  float w3r = w3[lane];
  __syncthreads();

  // ---- L = x * w1 in registers: lane (kc,h) owns half-column kc ----
  float4 a0 = {0.f, 0.f, 0.f, 0.f}, a1 = a0, a2 = a0, a3 = a0;
  #pragma unroll
  for (int j = 0; j < 32; ++j) {
    float wv = R1[j * 36 + kc];           // w1[j][kc]
    const float* xc = R0 + j * 36 + hb;   // x[j][i] = x[i][j]
    axpy4(a0, wv, *(const float4*)(xc));
    axpy4(a1, wv, *(const float4*)(xc + 4));
    axpy4(a2, wv, *(const float4*)(xc + 8));
    axpy4(a3, wv, *(const float4*)(xc + 12));
  }
  __syncthreads();                        // all x reads done
  *(float4*)(R0 + kc * 36 + hb)      = a0;
  *(float4*)(R0 + kc * 36 + hb + 4)  = a1;
  *(float4*)(R0 + kc * 36 + hb + 8)  = a2;
  *(float4*)(R0 + kc * 36 + hb + 12) = a3;
  __syncthreads();

  // ---- X1[:,kc] = sum_k w1[k][:] * L[k][kc] ----
  float Lc[32];
  #pragma unroll
  for (int c4 = 0; c4 < 8; ++c4) {
    float4 v = *(const float4*)(R0 + kc * 36 + 4 * c4);
    Lc[4 * c4] = v.x; Lc[4 * c4 + 1] = v.y; Lc[4 * c4 + 2] = v.z; Lc[4 * c4 + 3] = v.w;
  }
  a0 = {0.f, 0.f, 0.f, 0.f}; a1 = a0; a2 = a0; a3 = a0;
  #pragma unroll
  for (int kk = 0; kk < 32; ++kk) {
    float lv = Lc[kk];
    const float* wr = R1 + kk * 36 + hb;  // w1[kk][i]
    axpy4(a0, lv, *(const float4*)(wr));
    axpy4(a1, lv, *(const float4*)(wr + 4));
    axpy4(a2, lv, *(const float4*)(wr + 8));
    axpy4(a3, lv, *(const float4*)(wr + 12));
  }
  float nv = dot4(a0, a0) + dot4(a1, a1) + dot4(a2, a2) + dot4(a3, a3);
  nv += shfl_xor_f(nv, 1);
  __syncthreads();                        // L & w1 reads done
  // write G = X1 over R0; stage w2 over dead w1
  *(float4*)(R0 + kc * 36 + hb)      = a0;
  *(float4*)(R0 + kc * 36 + hb + 4)  = a1;
  *(float4*)(R0 + kc * 36 + hb + 8)  = a2;
  *(float4*)(R0 + kc * 36 + hb + 12) = a3;
  if (h == 0) NRM[kc] = nv;
  #pragma unroll
  for (int t = 0; t < 8; ++t) {
    int idx = lane + 64 * t;
    int j = idx >> 4, a = idx & 15;
    R1[a * 36 + j] = w2[idx];             // w2 col a contiguous
  }
  __syncthreads();

  // ---- eig #1: one-sided Jacobi on G (n=32) ----
  jac32(R0, NRM, lane);

  // ---- Z[:,k] = (w2^T g_k) * sqrt(mu)/lam, Z @ R1+576 stride 20 ----
  {
    float g[16];
    #pragma unroll
    for (int c = 0; c < 4; ++c) {
      float4 v = *(const float4*)(R0 + kc * 36 + hb + 4 * c);
      g[4 * c] = v.x; g[4 * c + 1] = v.y; g[4 * c + 2] = v.z; g[4 * c + 3] = v.w;
    }
    float dpp = 0.f;
    #pragma unroll
    for (int i = 0; i < 16; ++i) dpp += g[i] * g[i];
    dpp += shfl_xor_f(dpp, 1);
    float lam = __builtin_amdgcn_sqrtf(dpp);
    float mu  = fmaxf(lam, 1e-4f);
    float sc  = __builtin_amdgcn_sqrtf(mu) * __builtin_amdgcn_rcpf(fmaxf(lam, 1e-30f));
    #pragma unroll
    for (int a = 0; a < 16; ++a) {
      const float* wr = R1 + a * 36 + hb;
      float part = 0.f;
      #pragma unroll
      for (int c = 0; c < 4; ++c) {
        float4 wv = *(const float4*)(wr + 4 * c);
        part += g[4 * c] * wv.x + g[4 * c + 1] * wv.y + g[4 * c + 2] * wv.z + g[4 * c + 3] * wv.w;
      }
      part += shfl_xor_f(part, 1);
      if (h == 0) R1[576 + kc * 20 + a] = part * sc;
    }
  }
  __syncthreads();

  // ---- M2 = Z Z^T (16x16) into R0 stride 20; stage w3 @ R0+1024 ----
  {
    const int a = lane & 15, b0 = (lane >> 4) * 4;
    float m0 = 0.f, m1 = 0.f, m2 = 0.f, m3 = 0.f;
    #pragma unroll
    for (int kk = 0; kk < 32; ++kk) {
      float za = R1[576 + kk * 20 + a];
      float4 zb = *(const float4*)(R1 + 576 + kk * 20 + b0);
      m0 += za * zb.x; m1 += za * zb.y; m2 += za * zb.z; m3 += za * zb.w;
    }
    R0[(b0 + 0) * 20 + a] = m0;
    R0[(b0 + 1) * 20 + a] = m1;
    R0[(b0 + 2) * 20 + a] = m2;
    R0[(b0 + 3) * 20 + a] = m3;
    R0[1024 + (lane & 3) * 20 + (lane >> 2)] = w3r;   // w3 col-major
  }
  __syncthreads();

  // ---- norms of M2 columns ----
  if (lane < 32) {
    int cc = lane >> 1;
    float4 v0 = *(const float4*)(R0 + cc * 20 + 8 * h);
    float4 v1 = *(const float4*)(R0 + cc * 20 + 8 * h + 4);
    float n2 = dot4(v0, v0) + dot4(v1, v1);
    n2 += shfl_xor_f(n2, 1);
    if (h == 0) NRM[cc] = n2;
  }
  __syncthreads();

  // ---- eig #2: one-sided Jacobi on M2 (n=16) ----
  jac16(R0, NRM, lane);

  // ---- Y[a][k] = (w3_col_a . g2_k) * sqrt(mu2)/lam2, Y @ R1[0..64) ----
  {
    const int k3 = (lane >> 2) & 15, a3 = lane & 3;
    float dpp2 = 0.f, dotv = 0.f;
    #pragma unroll
    for (int c = 0; c < 4; ++c) {
      float4 gv = *(const float4*)(R0 + k3 * 20 + 4 * c);
      float4 wv = *(const float4*)(R0 + 1024 + a3 * 20 + 4 * c);
      dpp2 += dot4(gv, gv);
      dotv += dot4(gv, wv);
    }
    float lam2 = __builtin_amdgcn_sqrtf(dpp2);
    float mu2  = fmaxf(lam2, 1e-4f);
    float sc2  = __builtin_amdgcn_sqrtf(mu2) * __builtin_amdgcn_rcpf(fmaxf(lam2, 1e-30f));
    __syncthreads();                      // M2/w3 reads done before Y write (R1 dead)
    R1[k3 * 4 + a3] = dotv * sc2;         // Y, k-major stride 4
  }
  __syncthreads();
  if (lane < 16) {
    int a = lane >> 2, b2 = lane & 3;
    float s = 0.f;
    #pragma unroll
    for (int kk = 0; kk < 16; ++kk)
      s += R1[kk * 4 + a] * R1[kk * 4 + b2];
    R1[64 + lane] = s;                    // X3
  }
  __syncthreads();

  // ---- stage 3: serial 4x4 two-sided Jacobi + LogEig + fc + log_softmax ----
  if (lane == 0) {
    float Am[4][4], V[4][4];
    float maxd = 0.f;
    #pragma unroll
    for (int i = 0; i < 4; ++i) {
      #pragma unroll
      for (int j = 0; j < 4; ++j) {
        Am[i][j] = R1[64 + i * 4 + j];
        V[i][j] = (i == j) ? 1.f : 0.f;
      }
      maxd = fmaxf(maxd, fabsf(Am[i][i]));
    }
    float tol3 = 1e-7f * maxd;
    for (int sw = 0; sw < MAXSW4; ++sw) {
      bool any = false;
      #pragma unroll
      for (int p = 0; p < 3; ++p) {
        #pragma unroll
        for (int q = p + 1; q < 4; ++q) {
          float apq = Am[p][q];
          if (fabsf(apq) > tol3) {
            any = true;
            float c, s;
            rot_cs(apq, Am[p][p], Am[q][q], c, s);
            #pragma unroll
            for (int j = 0; j < 4; ++j) {
              float ap = Am[p][j], aq = Am[q][j];
              Am[p][j] = c * ap - s * aq;
              Am[q][j] = s * ap + c * aq;
            }
            #pragma unroll
            for (int i = 0; i < 4; ++i) {
              float ap = Am[i][p], aq = Am[i][q];
              Am[i][p] = c * ap - s * aq;
              Am[i][q] = s * ap + c * aq;
              float up = V[i][p], uq = V[i][q];
              V[i][p] = c * up - s * uq;
              V[i][q] = s * up + c * uq;
            }
          }
        }
      }
      if (!any) break;
    }
    float lm[4];
    #pragma unroll
    for (int i = 0; i < 4; ++i) lm[i] = logf(fmaxf(Am[i][i], 1e-10f));
    float feat[16];
    #pragma unroll
    for (int i = 0; i < 4; ++i)
      #pragma unroll
      for (int j = 0; j < 4; ++j) {
        float acc2 = 0.f;
        #pragma unroll
        for (int kk = 0; kk < 4; ++kk) acc2 += V[i][kk] * lm[kk] * V[j][kk];
        feat[i * 4 + j] = acc2;
      }
    float z0 = 0.f, z1 = 0.f;
    #pragma unroll
    for (int f = 0; f < 16; ++f) {
      z0 += feat[f] * fcw[f * 2 + 0];
      z1 += feat[f] * fcw[f * 2 + 1];
    }
    float mx = fmaxf(z0, z1);
    float lse = mx + logf(expf(z0 - mx) + expf(z1 - mx));
    out[b * 2 + 0] = z0 - lse;
    out[b * 2 + 1] = z1 - lse;
    float* fo = out + (size_t)2 * B + (size_t)b * 16;
    #pragma unroll
    for (int f = 0; f < 16; ++f) fo[f] = feat[f];
  }
}

extern "C" void kernel_launch(void* const* d_in, const int* in_sizes, int n_in,
                              void* d_out, int out_size, void* d_ws, size_t ws_size,
                              hipStream_t stream) {
  (void)n_in; (void)d_ws; (void)ws_size; (void)out_size;
  const float* x   = (const float*)d_in[0];
  const float* w1  = (const float*)d_in[1];
  const float* w2  = (const float*)d_in[2];
  const float* w3  = (const float*)d_in[3];
  const float* fcw = (const float*)d_in[4];
  float* out = (float*)d_out;
  int B = in_sizes[0] / 1024;
  spdnet_kernel<<<B, 64, 0, stream>>>(x, w1, w2, w3, fcw, out, B);
}